// Round 9
// baseline (143.552 us; speedup 1.0000x reference)
//
#include <hip/hip_runtime.h>

#define N_NODES   50000
#define N_EDGES   640000
#define DIM       128
#define NUM_GRAPHS 64
#define SLOTS     64   // max in-degree slot capacity; P(deg>=64 | lambda=12.8) ~ 3e-23/node
#define GEMM1_BLOCKS 196   // ceil(N_NODES/256)
#define FILL_BLOCKS  313   // ceil(N_EDGES/4/512)

typedef __attribute__((ext_vector_type(8))) short          s16x8;
typedef __attribute__((ext_vector_type(8))) unsigned short u16x8;
typedef __attribute__((ext_vector_type(4))) float          f32x4;

__device__ inline float bf2f(unsigned short u) {
    unsigned v = ((unsigned)u) << 16;
    float f;
    __builtin_memcpy(&f, &v, 4);
    return f;
}
__device__ inline unsigned short f2bf(float f) {
    unsigned u;
    __builtin_memcpy(&u, &f, 4);
    u = (u + 0x7fffu + ((u >> 16) & 1u)) >> 16;   // RNE
    return (unsigned short)u;
}

// ================================================================ weight prep + zeroing
__global__ __launch_bounds__(128) void k_prep_w(const float* __restrict__ W1,
                                                const float* __restrict__ W2,
                                                unsigned short* __restrict__ Wt1,
                                                unsigned short* __restrict__ Wt2,
                                                int* __restrict__ cnt,
                                                float* __restrict__ pooled) {
    int k = blockIdx.x & 127;
    const float*    W  = (blockIdx.x < DIM) ? W1 : W2;
    unsigned short* Wt = (blockIdx.x < DIM) ? Wt1 : Wt2;
    int n = threadIdx.x;
    Wt[n * DIM + k] = f2bf(W[k * DIM + n]);

    int gid = blockIdx.x * 128 + threadIdx.x;          // 32768 threads
    for (int i = gid; i < N_NODES; i += 32768) cnt[i] = 0;
    if (gid < NUM_GRAPHS * DIM) pooled[gid] = 0.f;
}

// ================================================================ fill_slots || GEMM1 (block-range fused)
__global__ __launch_bounds__(512) void k_fill_gemm1(const int* __restrict__ src,
                                                    const int* __restrict__ dst,
                                                    int* __restrict__ cnt,
                                                    unsigned short* __restrict__ slots,
                                                    const float* __restrict__ x,
                                                    const unsigned short* __restrict__ Wt1,
                                                    unsigned short* __restrict__ H1) {
    __shared__ unsigned short wsh[DIM][136];   // 272B row stride (gemm blocks only)
    const int tid = threadIdx.x;

    if (blockIdx.x >= GEMM1_BLOCKS) {
        int e0 = ((blockIdx.x - GEMM1_BLOCKS) * 512 + tid) * 4;
        if (e0 >= N_EDGES) return;
        int4 s4 = *reinterpret_cast<const int4*>(src + e0);
        int4 d4 = *reinterpret_cast<const int4*>(dst + e0);
        int p0 = atomicAdd(&cnt[d4.x], 1);
        int p1 = atomicAdd(&cnt[d4.y], 1);
        int p2 = atomicAdd(&cnt[d4.z], 1);
        int p3 = atomicAdd(&cnt[d4.w], 1);
        if (p0 < SLOTS) slots[d4.x * SLOTS + p0] = (unsigned short)s4.x;
        if (p1 < SLOTS) slots[d4.y * SLOTS + p1] = (unsigned short)s4.y;
        if (p2 < SLOTS) slots[d4.z * SLOTS + p2] = (unsigned short)s4.z;
        if (p3 < SLOTS) slots[d4.w * SLOTS + p3] = (unsigned short)s4.w;
        return;
    }

    // ---------------- GEMM1 (fp32 A -> bf16) ----------------
    #pragma unroll
    for (int i = 0; i < 4; i++) {
        int off = tid * 8 + i * 4096;
        int r = off >> 7, cc = off & 127;
        u16x8 v = *reinterpret_cast<const u16x8*>(Wt1 + off);
        *reinterpret_cast<u16x8*>(&wsh[r][cc]) = v;
    }
    __syncthreads();

    const int wid  = tid >> 6;
    const int lane = tid & 63;
    const int l15  = lane & 15;
    const int lk   = lane >> 4;
    const int row0 = blockIdx.x * 256 + wid * 32;

    f32x4 acc[2][8];
    #pragma unroll
    for (int a = 0; a < 2; a++)
        #pragma unroll
        for (int n = 0; n < 8; n++) acc[a][n] = (f32x4){0.f, 0.f, 0.f, 0.f};

    const long long r0 = min(row0 + l15,      N_NODES - 1);
    const long long r1 = min(row0 + 16 + l15, N_NODES - 1);

    #pragma unroll
    for (int kk = 0; kk < 4; kk++) {
        const int kb = kk * 32 + lk * 8;
        s16x8 a0, a1;
        const float4 p0 = *reinterpret_cast<const float4*>(x + r0 * DIM + kb);
        const float4 q0 = *reinterpret_cast<const float4*>(x + r0 * DIM + kb + 4);
        const float4 p1 = *reinterpret_cast<const float4*>(x + r1 * DIM + kb);
        const float4 q1 = *reinterpret_cast<const float4*>(x + r1 * DIM + kb + 4);
        a0[0]=(short)f2bf(p0.x); a0[1]=(short)f2bf(p0.y); a0[2]=(short)f2bf(p0.z); a0[3]=(short)f2bf(p0.w);
        a0[4]=(short)f2bf(q0.x); a0[5]=(short)f2bf(q0.y); a0[6]=(short)f2bf(q0.z); a0[7]=(short)f2bf(q0.w);
        a1[0]=(short)f2bf(p1.x); a1[1]=(short)f2bf(p1.y); a1[2]=(short)f2bf(p1.z); a1[3]=(short)f2bf(p1.w);
        a1[4]=(short)f2bf(q1.x); a1[5]=(short)f2bf(q1.y); a1[6]=(short)f2bf(q1.z); a1[7]=(short)f2bf(q1.w);
        #pragma unroll
        for (int n = 0; n < 8; n++) {
            s16x8 b = *reinterpret_cast<const s16x8*>(&wsh[n * 16 + l15][kb]);
            acc[0][n] = __builtin_amdgcn_mfma_f32_16x16x32_bf16(a0, b, acc[0][n], 0, 0, 0);
            acc[1][n] = __builtin_amdgcn_mfma_f32_16x16x32_bf16(a1, b, acc[1][n], 0, 0, 0);
        }
    }

    #pragma unroll
    for (int rh = 0; rh < 2; rh++) {
        #pragma unroll
        for (int j = 0; j < 4; j++) {
            int row = row0 + rh * 16 + lk * 4 + j;
            if (row < N_NODES) {
                #pragma unroll
                for (int n = 0; n < 8; n++)
                    H1[(long long)row * DIM + n * 16 + l15] = f2bf(acc[rh][n][j]);
            }
        }
    }
}

// ================================================================ bf16 MFMA GEMM (streaming, bf16 in)
__global__ __launch_bounds__(512) void k_gemm2(const unsigned short* __restrict__ Ab,
                                               const unsigned short* __restrict__ Wt,
                                               unsigned short* __restrict__ H) {
    __shared__ unsigned short wsh[DIM][136];
    const int tid = threadIdx.x;

    #pragma unroll
    for (int i = 0; i < 4; i++) {
        int off = tid * 8 + i * 4096;
        int r = off >> 7, cc = off & 127;
        u16x8 v = *reinterpret_cast<const u16x8*>(Wt + off);
        *reinterpret_cast<u16x8*>(&wsh[r][cc]) = v;
    }
    __syncthreads();

    const int wid  = tid >> 6;
    const int lane = tid & 63;
    const int l15  = lane & 15;
    const int lk   = lane >> 4;
    const int row0 = blockIdx.x * 256 + wid * 32;

    f32x4 acc[2][8];
    #pragma unroll
    for (int a = 0; a < 2; a++)
        #pragma unroll
        for (int n = 0; n < 8; n++) acc[a][n] = (f32x4){0.f, 0.f, 0.f, 0.f};

    const long long r0 = min(row0 + l15,      N_NODES - 1);
    const long long r1 = min(row0 + 16 + l15, N_NODES - 1);

    #pragma unroll
    for (int kk = 0; kk < 4; kk++) {
        const int kb = kk * 32 + lk * 8;
        s16x8 a0 = *reinterpret_cast<const s16x8*>(Ab + r0 * DIM + kb);
        s16x8 a1 = *reinterpret_cast<const s16x8*>(Ab + r1 * DIM + kb);
        #pragma unroll
        for (int n = 0; n < 8; n++) {
            s16x8 b = *reinterpret_cast<const s16x8*>(&wsh[n * 16 + l15][kb]);
            acc[0][n] = __builtin_amdgcn_mfma_f32_16x16x32_bf16(a0, b, acc[0][n], 0, 0, 0);
            acc[1][n] = __builtin_amdgcn_mfma_f32_16x16x32_bf16(a1, b, acc[1][n], 0, 0, 0);
        }
    }

    #pragma unroll
    for (int rh = 0; rh < 2; rh++) {
        #pragma unroll
        for (int j = 0; j < 4; j++) {
            int row = row0 + rh * 16 + lk * 4 + j;
            if (row < N_NODES) {
                #pragma unroll
                for (int n = 0; n < 8; n++)
                    H[(long long)row * DIM + n * 16 + l15] = f2bf(acc[rh][n][j]);
            }
        }
    }
}

// ================================================================ wave-per-node gather body
// 64 lanes = 4 slot-ways x 16 feature-lanes. Returns acc[8]; ALL lanes hold the
// full sum after the xor-reduce (lanes 0-15 are the canonical copy).
__device__ inline void gather_wave(const int* __restrict__ cnt,
                                   const unsigned short* __restrict__ slots,
                                   const unsigned short* __restrict__ h,
                                   const float* __restrict__ bias,
                                   int n, int c, int way, float dn, float* acc) {
    if (way == 0) {
        float d2 = dn * dn;
        u16x8 hv = *reinterpret_cast<const u16x8*>(h + (size_t)n * DIM + c);
        #pragma unroll
        for (int j = 0; j < 8; j++) acc[j] = bf2f(hv[j]) * d2 + bias[c + j];
    } else {
        #pragma unroll
        for (int j = 0; j < 8; j++) acc[j] = 0.f;
    }

    const int m = min(cnt[n], SLOTS);
    const unsigned short* sl = slots + (size_t)n * SLOTS;

    int i = way;
    for (; i + 4 < m; i += 8) {
        int s0 = sl[i], s1 = sl[i + 4];
        float w0 = rsqrtf((float)cnt[s0] + 1.0f) * dn;
        float w1 = rsqrtf((float)cnt[s1] + 1.0f) * dn;
        u16x8 v0 = *reinterpret_cast<const u16x8*>(h + (size_t)s0 * DIM + c);
        u16x8 v1 = *reinterpret_cast<const u16x8*>(h + (size_t)s1 * DIM + c);
        #pragma unroll
        for (int j = 0; j < 8; j++) acc[j] += bf2f(v0[j]) * w0 + bf2f(v1[j]) * w1;
    }
    if (i < m) {
        int s0 = sl[i];
        float w0 = rsqrtf((float)cnt[s0] + 1.0f) * dn;
        u16x8 v0 = *reinterpret_cast<const u16x8*>(h + (size_t)s0 * DIM + c);
        #pragma unroll
        for (int j = 0; j < 8; j++) acc[j] += bf2f(v0[j]) * w0;
    }

    // fold the 4 ways
    #pragma unroll
    for (int j = 0; j < 8; j++) {
        acc[j] += __shfl_xor(acc[j], 16);
        acc[j] += __shfl_xor(acc[j], 32);
    }
}

// ================================================================ pull layer 1 (wave/node, relu, bf16 out)
__global__ __launch_bounds__(512) void k_pull1(const int* __restrict__ cnt,
                                               const unsigned short* __restrict__ slots,
                                               const unsigned short* __restrict__ h,
                                               const float* __restrict__ bias,
                                               unsigned short* __restrict__ outp) {
    const int tid  = threadIdx.x;
    const int n    = blockIdx.x * 8 + (tid >> 6);
    const int lane = tid & 63;
    const int way  = lane >> 4;
    const int c    = (lane & 15) << 3;

    float dn = rsqrtf((float)cnt[n] + 1.0f);
    float acc[8];
    gather_wave(cnt, slots, h, bias, n, c, way, dn, acc);

    if (way == 0) {
        u16x8 o;
        #pragma unroll
        for (int j = 0; j < 8; j++) o[j] = f2bf(fmaxf(acc[j], 0.f));
        *reinterpret_cast<u16x8*>(outp + (size_t)n * DIM + c) = o;
    }
}

// ================================================================ pull layer 2 + fused mean-pool stage 1
// 8 waves = 8 nodes per block; LDS pool for the <=2 graphs this window spans.
__global__ __launch_bounds__(512) void k_pull_pool(const int* __restrict__ cnt,
                                                   const unsigned short* __restrict__ slots,
                                                   const unsigned short* __restrict__ h,
                                                   const float* __restrict__ bias,
                                                   const int* __restrict__ batch,
                                                   float* __restrict__ pooled) {
    __shared__ float pool_l[2][DIM];
    const int tid  = threadIdx.x;
    const int base = blockIdx.x * 8;
    const int n    = base + (tid >> 6);
    const int lane = tid & 63;
    const int way  = lane >> 4;
    const int c    = (lane & 15) << 3;

    if (tid < 256) pool_l[tid >> 7][tid & 127] = 0.f;
    __syncthreads();

    float dn = rsqrtf((float)cnt[n] + 1.0f);
    float acc[8];
    gather_wave(cnt, slots, h, bias, n, c, way, dn, acc);   // z2 (no relu)

    const int g    = batch[n];
    const int gmin = batch[base];
    const int d    = g - gmin;

    if (way == 0) {
        if (d < 2) {
            #pragma unroll
            for (int j = 0; j < 8; j++) atomicAdd(&pool_l[d][c + j], acc[j]);
        } else {
            #pragma unroll
            for (int j = 0; j < 8; j++) atomicAdd(&pooled[g * DIM + c + j], acc[j]);
        }
    }
    __syncthreads();

    const int f = tid & 127;
    if (tid < 128) {
        atomicAdd(&pooled[gmin * DIM + f], pool_l[0][f]);
    } else if (tid < 256) {
        int gmax = batch[base + 7];
        if (gmax > gmin) atomicAdd(&pooled[(gmin + 1) * DIM + f], pool_l[1][f]);
    }
}

// ================================================================ pool stage 2: mean + linear + relu
__global__ __launch_bounds__(128) void k_pool2(const float* __restrict__ pooled,
                                               const int* __restrict__ batch,
                                               const float* __restrict__ Wlin,
                                               const float* __restrict__ blin,
                                               float* __restrict__ out) {
    int g = blockIdx.x;
    int t = threadIdx.x;
    __shared__ int se[2];
    __shared__ float pr[DIM];
    if (t < 2) {
        int target = g + t;
        int lo = 0, hi = N_NODES;
        while (lo < hi) { int mid = (lo + hi) >> 1; if (batch[mid] < target) lo = mid + 1; else hi = mid; }
        se[t] = lo;
    }
    __syncthreads();
    float inv_cnt = 1.0f / fmaxf((float)(se[1] - se[0]), 1.0f);
    pr[t] = pooled[g * DIM + t] * inv_cnt;
    __syncthreads();
    float acc = blin[t];
    #pragma unroll 8
    for (int k = 0; k < DIM; k++) acc += pr[k] * Wlin[k * DIM + t];
    out[g * DIM + t] = fmaxf(acc, 0.f);
}

// ================================================================ launch
extern "C" void kernel_launch(void* const* d_in, const int* in_sizes, int n_in,
                              void* d_out, int out_size, void* d_ws, size_t ws_size,
                              hipStream_t stream) {
    const float* x          = (const float*)d_in[0];
    const int*   edge_index = (const int*)d_in[1];
    const int*   batch      = (const int*)d_in[2];
    const float* W1         = (const float*)d_in[3];
    const float* b1         = (const float*)d_in[4];
    const float* W2         = (const float*)d_in[5];
    const float* b2         = (const float*)d_in[6];
    const float* Wlin       = (const float*)d_in[7];
    const float* blin       = (const float*)d_in[8];
    float*       out        = (float*)d_out;

    const int* src = edge_index;
    const int* dst = edge_index + N_EDGES;

    char* ws = (char*)d_ws;
    size_t off = 0;
    auto alloc = [&](size_t bytes) { void* p = ws + off; off = (off + bytes + 255) & ~255ULL; return p; };
    int*            cnt    = (int*)            alloc((size_t)N_NODES * 4);
    unsigned short* slots  = (unsigned short*) alloc((size_t)N_NODES * SLOTS * 2);
    float*          pooled = (float*)          alloc((size_t)NUM_GRAPHS * DIM * 4);
    unsigned short* Wt1    = (unsigned short*) alloc((size_t)DIM * DIM * 2);
    unsigned short* Wt2    = (unsigned short*) alloc((size_t)DIM * DIM * 2);
    unsigned short* H1     = (unsigned short*) alloc((size_t)N_NODES * DIM * 2);
    unsigned short* Z1     = (unsigned short*) alloc((size_t)N_NODES * DIM * 2);
    unsigned short* H2     = (unsigned short*) alloc((size_t)N_NODES * DIM * 2);

    const int pullBlocks = N_NODES / 8;                     // 6250 (exact)
    const int gemmBlocks = (N_NODES + 255) / 256;           // 196

    // ---- weight prep + zero cnt/pooled ----
    k_prep_w<<<2 * DIM, DIM, 0, stream>>>(W1, W2, Wt1, Wt2, cnt, pooled);

    // ---- adjacency fill || GEMM1 ----
    k_fill_gemm1<<<GEMM1_BLOCKS + FILL_BLOCKS, 512, 0, stream>>>(src, dst, cnt, slots, x, Wt1, H1);

    // ---- layer 1 gather ----
    k_pull1<<<pullBlocks, 512, 0, stream>>>(cnt, slots, H1, b1, Z1);

    // ---- GEMM2 ----
    k_gemm2<<<gemmBlocks, 512, 0, stream>>>(Z1, Wt2, H2);

    // ---- layer-2 gather + fused pool stage 1 ----
    k_pull_pool<<<pullBlocks, 512, 0, stream>>>(cnt, slots, H2, b2, batch, pooled);

    // ---- pool stage 2 ----
    k_pool2<<<NUM_GRAPHS, 128, 0, stream>>>(pooled, batch, Wlin, blin, out);
}

// Round 10
// 122.027 us; speedup vs baseline: 1.1764x; 1.1764x over previous
//
#include <hip/hip_runtime.h>

#define N_NODES   50000
#define N_EDGES   640000
#define DIM       128
#define NUM_GRAPHS 64
#define SLOTS     64   // max in-degree slot capacity; P(deg>=64 | lambda=12.8) ~ 3e-23/node
#define GEMM1_BLOCKS 196   // ceil(N_NODES/256)
#define FILL_BLOCKS  313   // ceil(N_EDGES/4/512)

typedef __attribute__((ext_vector_type(8))) short          s16x8;
typedef __attribute__((ext_vector_type(8))) unsigned short u16x8;
typedef __attribute__((ext_vector_type(4))) float          f32x4;

__device__ inline float bf2f(unsigned short u) {
    unsigned v = ((unsigned)u) << 16;
    float f;
    __builtin_memcpy(&f, &v, 4);
    return f;
}
__device__ inline unsigned short f2bf(float f) {
    unsigned u;
    __builtin_memcpy(&u, &f, 4);
    u = (u + 0x7fffu + ((u >> 16) & 1u)) >> 16;   // RNE
    return (unsigned short)u;
}

// ================================================================ weight prep + zeroing
__global__ __launch_bounds__(128) void k_prep_w(const float* __restrict__ W1,
                                                const float* __restrict__ W2,
                                                unsigned short* __restrict__ Wt1,
                                                unsigned short* __restrict__ Wt2,
                                                int* __restrict__ cnt,
                                                float* __restrict__ pooled) {
    int k = blockIdx.x & 127;
    const float*    W  = (blockIdx.x < DIM) ? W1 : W2;
    unsigned short* Wt = (blockIdx.x < DIM) ? Wt1 : Wt2;
    int n = threadIdx.x;
    Wt[n * DIM + k] = f2bf(W[k * DIM + n]);

    int gid = blockIdx.x * 128 + threadIdx.x;          // 32768 threads
    for (int i = gid; i < N_NODES; i += 32768) cnt[i] = 0;
    if (gid < NUM_GRAPHS * DIM) pooled[gid] = 0.f;
}

// ================================================================ fill_slots || GEMM1 (block-range fused)
__global__ __launch_bounds__(512) void k_fill_gemm1(const int* __restrict__ src,
                                                    const int* __restrict__ dst,
                                                    int* __restrict__ cnt,
                                                    unsigned short* __restrict__ slots,
                                                    const float* __restrict__ x,
                                                    const unsigned short* __restrict__ Wt1,
                                                    unsigned short* __restrict__ H1) {
    __shared__ unsigned short wsh[DIM][136];   // 272B row stride (gemm blocks only)
    const int tid = threadIdx.x;

    if (blockIdx.x >= GEMM1_BLOCKS) {
        int e0 = ((blockIdx.x - GEMM1_BLOCKS) * 512 + tid) * 4;
        if (e0 >= N_EDGES) return;
        int4 s4 = *reinterpret_cast<const int4*>(src + e0);
        int4 d4 = *reinterpret_cast<const int4*>(dst + e0);
        int p0 = atomicAdd(&cnt[d4.x], 1);
        int p1 = atomicAdd(&cnt[d4.y], 1);
        int p2 = atomicAdd(&cnt[d4.z], 1);
        int p3 = atomicAdd(&cnt[d4.w], 1);
        if (p0 < SLOTS) slots[d4.x * SLOTS + p0] = (unsigned short)s4.x;
        if (p1 < SLOTS) slots[d4.y * SLOTS + p1] = (unsigned short)s4.y;
        if (p2 < SLOTS) slots[d4.z * SLOTS + p2] = (unsigned short)s4.z;
        if (p3 < SLOTS) slots[d4.w * SLOTS + p3] = (unsigned short)s4.w;
        return;
    }

    // ---------------- GEMM1 (fp32 A -> bf16) ----------------
    #pragma unroll
    for (int i = 0; i < 4; i++) {
        int off = tid * 8 + i * 4096;
        int r = off >> 7, cc = off & 127;
        u16x8 v = *reinterpret_cast<const u16x8*>(Wt1 + off);
        *reinterpret_cast<u16x8*>(&wsh[r][cc]) = v;
    }
    __syncthreads();

    const int wid  = tid >> 6;
    const int lane = tid & 63;
    const int l15  = lane & 15;
    const int lk   = lane >> 4;
    const int row0 = blockIdx.x * 256 + wid * 32;

    f32x4 acc[2][8];
    #pragma unroll
    for (int a = 0; a < 2; a++)
        #pragma unroll
        for (int n = 0; n < 8; n++) acc[a][n] = (f32x4){0.f, 0.f, 0.f, 0.f};

    const long long r0 = min(row0 + l15,      N_NODES - 1);
    const long long r1 = min(row0 + 16 + l15, N_NODES - 1);

    #pragma unroll
    for (int kk = 0; kk < 4; kk++) {
        const int kb = kk * 32 + lk * 8;
        s16x8 a0, a1;
        const float4 p0 = *reinterpret_cast<const float4*>(x + r0 * DIM + kb);
        const float4 q0 = *reinterpret_cast<const float4*>(x + r0 * DIM + kb + 4);
        const float4 p1 = *reinterpret_cast<const float4*>(x + r1 * DIM + kb);
        const float4 q1 = *reinterpret_cast<const float4*>(x + r1 * DIM + kb + 4);
        a0[0]=(short)f2bf(p0.x); a0[1]=(short)f2bf(p0.y); a0[2]=(short)f2bf(p0.z); a0[3]=(short)f2bf(p0.w);
        a0[4]=(short)f2bf(q0.x); a0[5]=(short)f2bf(q0.y); a0[6]=(short)f2bf(q0.z); a0[7]=(short)f2bf(q0.w);
        a1[0]=(short)f2bf(p1.x); a1[1]=(short)f2bf(p1.y); a1[2]=(short)f2bf(p1.z); a1[3]=(short)f2bf(p1.w);
        a1[4]=(short)f2bf(q1.x); a1[5]=(short)f2bf(q1.y); a1[6]=(short)f2bf(q1.z); a1[7]=(short)f2bf(q1.w);
        #pragma unroll
        for (int n = 0; n < 8; n++) {
            s16x8 b = *reinterpret_cast<const s16x8*>(&wsh[n * 16 + l15][kb]);
            acc[0][n] = __builtin_amdgcn_mfma_f32_16x16x32_bf16(a0, b, acc[0][n], 0, 0, 0);
            acc[1][n] = __builtin_amdgcn_mfma_f32_16x16x32_bf16(a1, b, acc[1][n], 0, 0, 0);
        }
    }

    #pragma unroll
    for (int rh = 0; rh < 2; rh++) {
        #pragma unroll
        for (int j = 0; j < 4; j++) {
            int row = row0 + rh * 16 + lk * 4 + j;
            if (row < N_NODES) {
                #pragma unroll
                for (int n = 0; n < 8; n++)
                    H1[(long long)row * DIM + n * 16 + l15] = f2bf(acc[rh][j == 0 ? n : n][j]);
            }
        }
    }
}

// ================================================================ bf16 MFMA GEMM (streaming, bf16 in)
__global__ __launch_bounds__(512) void k_gemm2(const unsigned short* __restrict__ Ab,
                                               const unsigned short* __restrict__ Wt,
                                               unsigned short* __restrict__ H) {
    __shared__ unsigned short wsh[DIM][136];
    const int tid = threadIdx.x;

    #pragma unroll
    for (int i = 0; i < 4; i++) {
        int off = tid * 8 + i * 4096;
        int r = off >> 7, cc = off & 127;
        u16x8 v = *reinterpret_cast<const u16x8*>(Wt + off);
        *reinterpret_cast<u16x8*>(&wsh[r][cc]) = v;
    }
    __syncthreads();

    const int wid  = tid >> 6;
    const int lane = tid & 63;
    const int l15  = lane & 15;
    const int lk   = lane >> 4;
    const int row0 = blockIdx.x * 256 + wid * 32;

    f32x4 acc[2][8];
    #pragma unroll
    for (int a = 0; a < 2; a++)
        #pragma unroll
        for (int n = 0; n < 8; n++) acc[a][n] = (f32x4){0.f, 0.f, 0.f, 0.f};

    const long long r0 = min(row0 + l15,      N_NODES - 1);
    const long long r1 = min(row0 + 16 + l15, N_NODES - 1);

    #pragma unroll
    for (int kk = 0; kk < 4; kk++) {
        const int kb = kk * 32 + lk * 8;
        s16x8 a0 = *reinterpret_cast<const s16x8*>(Ab + r0 * DIM + kb);
        s16x8 a1 = *reinterpret_cast<const s16x8*>(Ab + r1 * DIM + kb);
        #pragma unroll
        for (int n = 0; n < 8; n++) {
            s16x8 b = *reinterpret_cast<const s16x8*>(&wsh[n * 16 + l15][kb]);
            acc[0][n] = __builtin_amdgcn_mfma_f32_16x16x32_bf16(a0, b, acc[0][n], 0, 0, 0);
            acc[1][n] = __builtin_amdgcn_mfma_f32_16x16x32_bf16(a1, b, acc[1][n], 0, 0, 0);
        }
    }

    #pragma unroll
    for (int rh = 0; rh < 2; rh++) {
        #pragma unroll
        for (int j = 0; j < 4; j++) {
            int row = row0 + rh * 16 + lk * 4 + j;
            if (row < N_NODES) {
                #pragma unroll
                for (int n = 0; n < 8; n++)
                    H[(long long)row * DIM + n * 16 + l15] = f2bf(acc[rh][n][j]);
            }
        }
    }
}

// ================================================================ shared gather body (16 lanes/node, 4x unroll)
__device__ inline void gather_node(const int* __restrict__ cnt,
                                   const unsigned short* __restrict__ slots,
                                   const unsigned short* __restrict__ h,
                                   const float* __restrict__ bias,
                                   int n, int c, float dn, float* acc) {
    float d2 = dn * dn;
    u16x8 hv = *reinterpret_cast<const u16x8*>(h + (size_t)n * DIM + c);
    #pragma unroll
    for (int j = 0; j < 8; j++) acc[j] = bf2f(hv[j]) * d2 + bias[c + j];

    const int m = min(cnt[n], SLOTS);
    const unsigned short* sl = slots + (size_t)n * SLOTS;

    int i = 0;
    for (; i + 3 < m; i += 4) {
        int s0 = sl[i], s1 = sl[i + 1], s2 = sl[i + 2], s3 = sl[i + 3];
        float w0 = rsqrtf((float)cnt[s0] + 1.0f) * dn;
        float w1 = rsqrtf((float)cnt[s1] + 1.0f) * dn;
        float w2 = rsqrtf((float)cnt[s2] + 1.0f) * dn;
        float w3 = rsqrtf((float)cnt[s3] + 1.0f) * dn;
        u16x8 v0 = *reinterpret_cast<const u16x8*>(h + (size_t)s0 * DIM + c);
        u16x8 v1 = *reinterpret_cast<const u16x8*>(h + (size_t)s1 * DIM + c);
        u16x8 v2 = *reinterpret_cast<const u16x8*>(h + (size_t)s2 * DIM + c);
        u16x8 v3 = *reinterpret_cast<const u16x8*>(h + (size_t)s3 * DIM + c);
        #pragma unroll
        for (int j = 0; j < 8; j++)
            acc[j] += (bf2f(v0[j]) * w0 + bf2f(v1[j]) * w1) +
                      (bf2f(v2[j]) * w2 + bf2f(v3[j]) * w3);
    }
    for (; i < m; i++) {
        int s0 = sl[i];
        float w0 = rsqrtf((float)cnt[s0] + 1.0f) * dn;
        u16x8 v0 = *reinterpret_cast<const u16x8*>(h + (size_t)s0 * DIM + c);
        #pragma unroll
        for (int j = 0; j < 8; j++) acc[j] += bf2f(v0[j]) * w0;
    }
}

// ================================================================ pull layer 1 (relu, bf16 out)
__global__ __launch_bounds__(256) void k_pull1(const int* __restrict__ cnt,
                                               const unsigned short* __restrict__ slots,
                                               const unsigned short* __restrict__ h,
                                               const float* __restrict__ bias,
                                               unsigned short* __restrict__ outp) {
    int gid = blockIdx.x * blockDim.x + threadIdx.x;
    int n = gid >> 4;
    if (n >= N_NODES) return;
    int c = (gid & 15) << 3;

    float dn = rsqrtf((float)cnt[n] + 1.0f);
    float acc[8];
    gather_node(cnt, slots, h, bias, n, c, dn, acc);

    u16x8 o;
    #pragma unroll
    for (int j = 0; j < 8; j++) o[j] = f2bf(fmaxf(acc[j], 0.f));
    *reinterpret_cast<u16x8*>(outp + (size_t)n * DIM + c) = o;
}

// ================================================================ pull layer 2 + fused mean-pool stage 1
// 256 threads = 16 nodes x 16 lanes; 4 rounds -> 64 nodes per block.
// LDS pool for the <=2 graphs this 64-node window spans; flush once per block.
__global__ __launch_bounds__(256) void k_pull_pool(const int* __restrict__ cnt,
                                                   const unsigned short* __restrict__ slots,
                                                   const unsigned short* __restrict__ h,
                                                   const float* __restrict__ bias,
                                                   const int* __restrict__ batch,
                                                   float* __restrict__ pooled) {
    __shared__ float pool_l[2][DIM];
    const int tid  = threadIdx.x;
    const int base = blockIdx.x * 64;
    const int c    = (tid & 15) << 3;

    pool_l[tid >> 7][tid & 127] = 0.f;
    __syncthreads();

    const int gmin = batch[min(base, N_NODES - 1)];

    #pragma unroll
    for (int r = 0; r < 4; r++) {
        int n = base + r * 16 + (tid >> 4);
        bool valid = n < N_NODES;
        int nn = min(n, N_NODES - 1);

        float dn = rsqrtf((float)cnt[nn] + 1.0f);
        float acc[8];
        gather_node(cnt, slots, h, bias, nn, c, dn, acc);   // z2 (no relu)
        if (!valid) {
            #pragma unroll
            for (int j = 0; j < 8; j++) acc[j] = 0.f;
        }

        const int g = batch[nn];
        const int d = g - gmin;

        // reduce 4 nodes within the wave when graph-uniform
        if (__all(g == __shfl(g, 0))) {
            #pragma unroll
            for (int j = 0; j < 8; j++) {
                acc[j] += __shfl_xor(acc[j], 16);
                acc[j] += __shfl_xor(acc[j], 32);
            }
            if ((tid & 63) < 16) {
                if (d < 2) {
                    #pragma unroll
                    for (int j = 0; j < 8; j++) atomicAdd(&pool_l[d][c + j], acc[j]);
                } else {
                    #pragma unroll
                    for (int j = 0; j < 8; j++) atomicAdd(&pooled[g * DIM + c + j], acc[j]);
                }
            }
        } else {
            if (d < 2) {
                #pragma unroll
                for (int j = 0; j < 8; j++) atomicAdd(&pool_l[d][c + j], acc[j]);
            } else {
                #pragma unroll
                for (int j = 0; j < 8; j++) atomicAdd(&pooled[g * DIM + c + j], acc[j]);
            }
        }
    }
    __syncthreads();

    const int f = tid & 127;
    if (tid < 128) {
        atomicAdd(&pooled[gmin * DIM + f], pool_l[0][f]);
    } else {
        int last = min(base + 63, N_NODES - 1);
        if (batch[last] > gmin) atomicAdd(&pooled[(gmin + 1) * DIM + f], pool_l[1][f]);
    }
}

// ================================================================ pool stage 2: mean + linear + relu
__global__ __launch_bounds__(128) void k_pool2(const float* __restrict__ pooled,
                                               const int* __restrict__ batch,
                                               const float* __restrict__ Wlin,
                                               const float* __restrict__ blin,
                                               float* __restrict__ out) {
    int g = blockIdx.x;
    int t = threadIdx.x;
    __shared__ int se[2];
    __shared__ float pr[DIM];
    if (t < 2) {
        int target = g + t;
        int lo = 0, hi = N_NODES;
        while (lo < hi) { int mid = (lo + hi) >> 1; if (batch[mid] < target) lo = mid + 1; else hi = mid; }
        se[t] = lo;
    }
    __syncthreads();
    float inv_cnt = 1.0f / fmaxf((float)(se[1] - se[0]), 1.0f);
    pr[t] = pooled[g * DIM + t] * inv_cnt;
    __syncthreads();
    float acc = blin[t];
    #pragma unroll 8
    for (int k = 0; k < DIM; k++) acc += pr[k] * Wlin[k * DIM + t];
    out[g * DIM + t] = fmaxf(acc, 0.f);
}

// ================================================================ launch
extern "C" void kernel_launch(void* const* d_in, const int* in_sizes, int n_in,
                              void* d_out, int out_size, void* d_ws, size_t ws_size,
                              hipStream_t stream) {
    const float* x          = (const float*)d_in[0];
    const int*   edge_index = (const int*)d_in[1];
    const int*   batch      = (const int*)d_in[2];
    const float* W1         = (const float*)d_in[3];
    const float* b1         = (const float*)d_in[4];
    const float* W2         = (const float*)d_in[5];
    const float* b2         = (const float*)d_in[6];
    const float* Wlin       = (const float*)d_in[7];
    const float* blin       = (const float*)d_in[8];
    float*       out        = (float*)d_out;

    const int* src = edge_index;
    const int* dst = edge_index + N_EDGES;

    char* ws = (char*)d_ws;
    size_t off = 0;
    auto alloc = [&](size_t bytes) { void* p = ws + off; off = (off + bytes + 255) & ~255ULL; return p; };
    int*            cnt    = (int*)            alloc((size_t)N_NODES * 4);
    unsigned short* slots  = (unsigned short*) alloc((size_t)N_NODES * SLOTS * 2);
    float*          pooled = (float*)          alloc((size_t)NUM_GRAPHS * DIM * 4);
    unsigned short* Wt1    = (unsigned short*) alloc((size_t)DIM * DIM * 2);
    unsigned short* Wt2    = (unsigned short*) alloc((size_t)DIM * DIM * 2);
    unsigned short* H1     = (unsigned short*) alloc((size_t)N_NODES * DIM * 2);
    unsigned short* Z1     = (unsigned short*) alloc((size_t)N_NODES * DIM * 2);
    unsigned short* H2     = (unsigned short*) alloc((size_t)N_NODES * DIM * 2);

    const int pull1Blocks = (N_NODES * 16 + 255) / 256;     // 3125
    const int poolBlocks  = (N_NODES + 63) / 64;            // 782
    const int gemmBlocks  = (N_NODES + 255) / 256;          // 196

    // ---- weight prep + zero cnt/pooled ----
    k_prep_w<<<2 * DIM, DIM, 0, stream>>>(W1, W2, Wt1, Wt2, cnt, pooled);

    // ---- adjacency fill || GEMM1 ----
    k_fill_gemm1<<<GEMM1_BLOCKS + FILL_BLOCKS, 512, 0, stream>>>(src, dst, cnt, slots, x, Wt1, H1);

    // ---- layer 1 gather ----
    k_pull1<<<pull1Blocks, 256, 0, stream>>>(cnt, slots, H1, b1, Z1);

    // ---- GEMM2 ----
    k_gemm2<<<gemmBlocks, 512, 0, stream>>>(Z1, Wt2, H2);

    // ---- layer-2 gather + fused pool stage 1 ----
    k_pull_pool<<<poolBlocks, 256, 0, stream>>>(cnt, slots, H2, b2, batch, pooled);

    // ---- pool stage 2 ----
    k_pool2<<<NUM_GRAPHS, 128, 0, stream>>>(pooled, batch, Wlin, blin, out);
}